// Round 7
// baseline (628.374 us; speedup 1.0000x reference)
//
#include <hip/hip_runtime.h>
#include <stdint.h>

typedef __attribute__((ext_vector_type(8))) _Float16 half8;  // MFMA f16 A/B frag (4 VGPRs)
typedef __attribute__((ext_vector_type(4))) float f32x4;     // MFMA C/D frag

// B=4, C=384, Q=384, H=256, K=256.  w1 is (256 k-rows, 768 h-cols):
//   W_h[k][h]=w1[k][h], W_u[k][h]=w1[k][256+h], W_hu[k][h]=w1[k][512+h]
// pre1[c,q,k] = sum_h (u*h)·W_hu + tu[q,k] + th'[c,k]      (th' = h·W_h + b1)
// out[c,q]    = leaky( sum_k leaky(pre1)·w2[k] + b2 )
// ws: [0,        393216)  fp16 [3][256][256] = W_h, W_u, W_hu   (k_convert)
//     [393216,  1966080)  tu  fp32 (1536,256)                   (k_pre)
//     [1966080, 3538944)  th' fp32 (1536,256)                   (k_pre)
//     [3538944, 5898240)  part fp32 (4*384*384), atomic-accumulated over kt

__device__ __forceinline__ float leaky(float x) { return fmaxf(x, 0.01f * x); }

template <int CTRL>
__device__ __forceinline__ float dpp_add(float x) {
  int t = __builtin_amdgcn_update_dpp(0, __float_as_int(x), CTRL, 0xF, 0xF, true);
  return x + __int_as_float(t);
}
// sum across the 16 lanes of an aligned 16-lane row (r = lane&15)
__device__ __forceinline__ float row16_sum(float p) {
  p = dpp_add<0xB1>(p);   // quad_perm xor1
  p = dpp_add<0x4E>(p);   // quad_perm xor2
  p = dpp_add<0x124>(p);  // row_ror:4
  p = dpp_add<0x128>(p);  // row_ror:8
  return p;
}

__device__ __forceinline__ half8 cvt8(const float* p) {
  float4 a0 = *(const float4*)p;
  float4 a1 = *(const float4*)(p + 4);
  half8 h;
  h[0] = (_Float16)a0.x; h[1] = (_Float16)a0.y;
  h[2] = (_Float16)a0.z; h[3] = (_Float16)a0.w;
  h[4] = (_Float16)a1.x; h[5] = (_Float16)a1.y;
  h[6] = (_Float16)a1.z; h[7] = (_Float16)a1.w;
  return h;
}

// ---------------- K0: split w1 -> fp16 [3][k][h]  (verified R3/R5) ------------------
__global__ void k_convert(const float* __restrict__ w1, unsigned int* __restrict__ ws) {
  int d = blockIdx.x * 256 + threadIdx.x;        // 98304 dwords
  int m = d >> 15;
  int rem = d & 32767;
  int k = rem >> 7;
  int h2 = (rem & 127) * 2;
  float x0 = w1[k * 768 + m * 256 + h2];
  float x1 = w1[k * 768 + m * 256 + h2 + 1];
  unsigned short p0 = __builtin_bit_cast(unsigned short, (_Float16)x0);
  unsigned short p1 = __builtin_bit_cast(unsigned short, (_Float16)x1);
  ws[d] = (unsigned int)p0 | ((unsigned int)p1 << 16);
}

// ---------------- K1: k_pre — tu = u·W_u^T ; th' = h·W_h^T + b1  --------------------
// 96 blocks: [0,48) -> tu, [48,96) -> th'. Block = 32 rows x 256 k; 4 waves split k.
// Same permuted-k convention as k_main: wave w, lane (quad,r): k = w*64 + 4r + j.
__global__ void __launch_bounds__(256) k_pre(
    const float* __restrict__ hp, const float* __restrict__ up,
    const _Float16* __restrict__ ws16, const float* __restrict__ b1,
    float* __restrict__ tu, float* __restrict__ th) {
  const int blk = blockIdx.x;
  const bool is_th = blk >= 48;
  const float* x = is_th ? hp : up;
  const _Float16* W = ws16 + (is_th ? 0 : 65536);
  float* dst = is_th ? th : tu;
  const int row0 = (is_th ? blk - 48 : blk) * 32;

  const int tid = threadIdx.x;
  const int w = tid >> 6, l = tid & 63, quad = l >> 4, r = l & 15;
  const int kbase = w * 64 + r * 4;

  half8 ufr[2][8];
#pragma unroll
  for (int i = 0; i < 2; ++i)
#pragma unroll
    for (int s = 0; s < 8; ++s)
      ufr[i][s] = cvt8(x + (row0 + i * 16 + r) * 256 + s * 32 + quad * 8);

  f32x4 acc[2][4];
#pragma unroll
  for (int i = 0; i < 2; ++i)
#pragma unroll
    for (int j = 0; j < 4; ++j) acc[i][j] = (f32x4){0.f, 0.f, 0.f, 0.f};
#pragma unroll
  for (int s = 0; s < 8; ++s)
#pragma unroll
    for (int j = 0; j < 4; ++j) {
      half8 wb = *(const half8*)(W + (kbase + j) * 256 + s * 32 + quad * 8);
#pragma unroll
      for (int i = 0; i < 2; ++i)
        acc[i][j] = __builtin_amdgcn_mfma_f32_16x16x32_f16(ufr[i][s], wb, acc[i][j], 0, 0, 0);
    }

  f32x4 bv = (f32x4){0.f, 0.f, 0.f, 0.f};
  if (is_th) bv = *(const f32x4*)(b1 + kbase);
#pragma unroll
  for (int i = 0; i < 2; ++i)
#pragma unroll
    for (int ii = 0; ii < 4; ++ii) {
      f32x4 o = {acc[i][0][ii] + bv[0], acc[i][1][ii] + bv[1],
                 acc[i][2][ii] + bv[2], acc[i][3][ii] + bv[3]};
      *(f32x4*)&dst[(row0 + i * 16 + quad * 4 + ii) * 256 + kbase] = o;
    }
}

// ---------------- K2: main. Block = 128 q x 64 k (kt-split) x 12 c ------------------
// 4 waves split q (wave w: q-rows w*32..w*32+31). Lane (quad,r): k = kt*64 + 4r + j.
// acc starts at ZERO (pure AGPR); tu/th' are added in the epilogue from L2.
// Arch-VGPR demand ~111 (<128): no spill at 2 waves/SIMD.
__global__ void __launch_bounds__(256, 2) k_main(
    const float* __restrict__ hp, const float* __restrict__ up,
    const _Float16* __restrict__ ws16,
    const float* __restrict__ tu, const float* __restrict__ th,
    const float* __restrict__ w2, float* __restrict__ part) {
  __shared__ __align__(16) _Float16 whuL[64 * 256];   // 32 KB, XOR-swizzled slots
  __shared__ __align__(16) _Float16 hlds[12 * 256];   // 6 KB

  const int tid = threadIdx.x;
  int t = blockIdx.x;                  // 1536 = kt(4) + 4*(qt(3) + 3*(cc(32) + 32*b(4)))
  const int kt = t & 3;  t >>= 2;
  const int qt = t % 3;  t /= 3;
  const int cc = t & 31;
  const int b = t >> 5;
  const int c0 = cc * 12;

  const int w = tid >> 6, l = tid & 63, quad = l >> 4, r = l & 15;
  const int kbase = kt * 64 + r * 4;   // lane's 4 k = kbase + j

  const _Float16* Whu = ws16 + 131072;

  // ---- stage W_hu k-slice -> LDS, swizzled: slot = (h>>3) ^ ((krel>>2)&7) ----
#pragma unroll
  for (int it = 0; it < 8; ++it) {
    int chunk = tid + it * 256;        // 2048 chunks of 8 halfs
    int krel = chunk >> 5;
    int slot = chunk & 31;
    int hsrc = (slot ^ ((krel >> 2) & 7)) * 8;
    half8 v = *(const half8*)(Whu + (kt * 64 + krel) * 256 + hsrc);
    *(half8*)&whuL[krel * 256 + slot * 8] = v;
  }
  // ---- stage h rows -> LDS fp16 ----
#pragma unroll
  for (int it = 0; it < 3; ++it) {
    int idx = tid + it * 256;          // 768 chunks of 4 halfs
    int c = idx >> 6;
    int hh = (idx & 63) * 4;
    float4 v = *(const float4*)(hp + (b * 384 + c0 + c) * 256 + hh);
    unsigned int lo = (unsigned int)__builtin_bit_cast(unsigned short, (_Float16)v.x) |
                      ((unsigned int)__builtin_bit_cast(unsigned short, (_Float16)v.y) << 16);
    unsigned int hi = (unsigned int)__builtin_bit_cast(unsigned short, (_Float16)v.z) |
                      ((unsigned int)__builtin_bit_cast(unsigned short, (_Float16)v.w) << 16);
    *(uint2*)&hlds[c * 256 + hh] = make_uint2(lo, hi);
  }

  // ---- resident u frags: q = qt*128 + w*32 + i*16 + r ----
  half8 ufr[2][8];
#pragma unroll
  for (int i = 0; i < 2; ++i) {
    const float* urow = up + (b * 384 + qt * 128 + w * 32 + i * 16 + r) * 256 + quad * 8;
#pragma unroll
    for (int s = 0; s < 8; ++s) ufr[i][s] = cvt8(urow + s * 32);
  }

  __syncthreads();   // whuL + hlds ready — the only barrier

  f32x4 w2v = *(const f32x4*)(w2 + kbase);
  const int rs = r & 7;          // reader-side slot swizzle
  const float* turow = tu + (b * 384 + qt * 128 + w * 32) * 256 + kbase;

  for (int cp = 0; cp < 6; ++cp) {
    f32x4 acc[2][2][4];
#pragma unroll
    for (int c2 = 0; c2 < 2; ++c2)
#pragma unroll
      for (int i = 0; i < 2; ++i)
#pragma unroll
        for (int j = 0; j < 4; ++j) acc[c2][i][j] = (f32x4){0.f, 0.f, 0.f, 0.f};

#pragma unroll
    for (int s = 0; s < 8; ++s) {
      half8 bf[4];
#pragma unroll
      for (int j = 0; j < 4; ++j) {
        int krel = r * 4 + j;
        int slot = (s * 4 + quad) ^ rs;
        bf[j] = *(const half8*)&whuL[krel * 256 + slot * 8];
      }
#pragma unroll
      for (int c2 = 0; c2 < 2; ++c2) {
        half8 hc = *(const half8*)&hlds[(2 * cp + c2) * 256 + s * 32 + quad * 8];
#pragma unroll
        for (int i = 0; i < 2; ++i) {
          half8 a = ufr[i][s] * hc;          // 4x v_pk_mul_f16, one live temp
#pragma unroll
          for (int j = 0; j < 4; ++j)
            acc[c2][i][j] =
                __builtin_amdgcn_mfma_f32_16x16x32_f16(a, bf[j], acc[c2][i][j], 0, 0, 0);
        }
      }
    }

    // epilogue: pre1 = acc + tu + th'; layer-2 partial -> atomicAdd into part
    f32x4 thv0 = *(const f32x4*)&th[(b * 384 + c0 + 2 * cp) * 256 + kbase];
    f32x4 thv1 = *(const f32x4*)&th[(b * 384 + c0 + 2 * cp + 1) * 256 + kbase];
    int cg = (b * 384 + c0 + 2 * cp) * 384 + qt * 128 + w * 32;
#pragma unroll
    for (int i = 0; i < 2; ++i)
#pragma unroll
      for (int ii = 0; ii < 4; ++ii) {
        f32x4 tuv = *(const f32x4*)(turow + (i * 16 + quad * 4 + ii) * 256);
        float p0 = 0.f, p1 = 0.f;
#pragma unroll
        for (int j = 0; j < 4; ++j) {
          float base = acc[0][i][j][ii] + tuv[j] + thv0[j];
          float t0 = fmaf(0.495f, fabsf(base), 0.505f * base);   // leaky
          p0 = fmaf(w2v[j], t0, p0);
          float base1 = acc[1][i][j][ii] + tuv[j] + thv1[j];
          float t1 = fmaf(0.495f, fabsf(base1), 0.505f * base1);
          p1 = fmaf(w2v[j], t1, p1);
        }
        p0 = row16_sum(p0);
        p1 = row16_sum(p1);
        if (r == 0) {
          atomicAdd(&part[cg + i * 16 + quad * 4 + ii], p0);
          atomicAdd(&part[cg + 384 + i * 16 + quad * 4 + ii], p1);
        }
      }
  }
}

// ---------------- K3: out = leaky(partial + b2) -------------------------------------
__global__ void k_final(const float* __restrict__ part, const float* __restrict__ b2,
                        float* __restrict__ out) {
  int i = blockIdx.x * 256 + threadIdx.x;        // 589824 exact
  out[i] = leaky(part[i] + b2[0]);
}

extern "C" void kernel_launch(void* const* d_in, const int* in_sizes, int n_in,
                              void* d_out, int out_size, void* d_ws, size_t ws_size,
                              hipStream_t stream) {
  const float* hp = (const float*)d_in[0];   // (4,384,256)
  const float* up = (const float*)d_in[1];   // (4,384,256)
  const float* w1 = (const float*)d_in[2];   // (256,768) — axis-0 is k
  const float* b1 = (const float*)d_in[3];   // (256,)
  const float* w2 = (const float*)d_in[4];   // (1,256)
  const float* b2 = (const float*)d_in[5];   // (1,)
  float* out = (float*)d_out;                // (4,384,384)

  _Float16* ws16 = (_Float16*)d_ws;                       // [0, 393216)
  float* tu = (float*)((char*)d_ws + 393216);             // (1536,256)
  float* th = (float*)((char*)d_ws + 1966080);            // (1536,256)
  float* part = (float*)((char*)d_ws + 3538944);          // (4*384*384)

  hipMemsetAsync(part, 0, 4 * 384 * 384 * sizeof(float), stream);
  k_convert<<<384, 256, 0, stream>>>(w1, (unsigned int*)d_ws);
  k_pre<<<96, 256, 0, stream>>>(hp, up, ws16, b1, tu, th);
  k_main<<<1536, 256, 0, stream>>>(hp, up, ws16, tu, th, w2, part);
  k_final<<<2304, 256, 0, stream>>>(part, b2, out);
}

// Round 8
// 434.994 us; speedup vs baseline: 1.4446x; 1.4446x over previous
//
#include <hip/hip_runtime.h>
#include <stdint.h>

typedef __attribute__((ext_vector_type(8))) _Float16 half8;  // MFMA f16 A/B frag (4 VGPRs)
typedef __attribute__((ext_vector_type(4))) float f32x4;     // MFMA C/D frag

// B=4, C=384, Q=384, H=256, K=256.  w1 is (256 k-rows, 768 h-cols):
//   W_h[k][h]=w1[k][h], W_u[k][h]=w1[k][256+h], W_hu[k][h]=w1[k][512+h]
// Identity (R3-verified): pre1[c,q,k] = sum_h u[q,h]*(h[c,h]*W_hu[k,h] + W_u[k,h]) + th'[c,k]
//                         out[c,q]    = leaky( sum_k leaky(pre1)*w2[k] + b2 )
// ws layout (bytes):
//   [0,        393216)   fp16 [3][256][256] = W_h, W_u, W_hu     (k_convert)
//   [393216,  1179648)   fp16 h16 (1536,256)                     (k_convert)
//   [1179648, 2752512)   fp32 th' (1536,256) = h·W_h^T + b1      (k_pre)
//   [2752512, 12189696)  fp32 part[4][4*384*384]  (per-kt partials, plain stores)

__device__ __forceinline__ float leaky(float x) { return fmaxf(x, 0.01f * x); }

template <int CTRL>
__device__ __forceinline__ float dpp_add(float x) {
  int t = __builtin_amdgcn_update_dpp(0, __float_as_int(x), CTRL, 0xF, 0xF, true);
  return x + __int_as_float(t);
}
// sum across the 16 lanes of an aligned 16-lane row (r = lane&15)
__device__ __forceinline__ float row16_sum(float p) {
  p = dpp_add<0xB1>(p);   // quad_perm xor1
  p = dpp_add<0x4E>(p);   // quad_perm xor2
  p = dpp_add<0x124>(p);  // row_ror:4
  p = dpp_add<0x128>(p);  // row_ror:8
  return p;
}

__device__ __forceinline__ half8 cvt8(const float* p) {
  float4 a0 = *(const float4*)p;
  float4 a1 = *(const float4*)(p + 4);
  half8 h;
  h[0] = (_Float16)a0.x; h[1] = (_Float16)a0.y;
  h[2] = (_Float16)a0.z; h[3] = (_Float16)a0.w;
  h[4] = (_Float16)a1.x; h[5] = (_Float16)a1.y;
  h[6] = (_Float16)a1.z; h[7] = (_Float16)a1.w;
  return h;
}

// ---------------- K0: w1 -> fp16 [3][k][h]  AND  h -> fp16 [row][h] -----------------
__global__ void k_convert(const float* __restrict__ w1, const float* __restrict__ hp,
                          unsigned int* __restrict__ ws) {
  int e = blockIdx.x * 256 + threadIdx.x;        // 294912 dwords total
  float x0, x1;
  if (e < 98304) {                               // weights: 98304 dwords
    int m = e >> 15;
    int rem = e & 32767;
    int k = rem >> 7;
    int h2 = (rem & 127) * 2;
    x0 = w1[k * 768 + m * 256 + h2];
    x1 = w1[k * 768 + m * 256 + h2 + 1];
  } else {                                       // h16: 196608 dwords
    int d = e - 98304;
    int h2 = (d & 127) * 2;
    int row = d >> 7;
    x0 = hp[row * 256 + h2];
    x1 = hp[row * 256 + h2 + 1];
  }
  unsigned short p0 = __builtin_bit_cast(unsigned short, (_Float16)x0);
  unsigned short p1 = __builtin_bit_cast(unsigned short, (_Float16)x1);
  ws[e] = (unsigned int)p0 | ((unsigned int)p1 << 16);
}

// ---------------- K1: k_pre — th' = h·W_h^T + b1  (48 blocks x 32 rows) -------------
__global__ void __launch_bounds__(256) k_pre(
    const _Float16* __restrict__ ws16, const _Float16* __restrict__ h16,
    const float* __restrict__ b1, float* __restrict__ th) {
  const int row0 = blockIdx.x * 32;
  const int tid = threadIdx.x;
  const int w = tid >> 6, l = tid & 63, quad = l >> 4, r = l & 15;
  const int kbase = w * 64 + r * 4;

  half8 ha[2][8];
#pragma unroll
  for (int i = 0; i < 2; ++i)
#pragma unroll
    for (int s = 0; s < 8; ++s)
      ha[i][s] = *(const half8*)(h16 + (row0 + i * 16 + r) * 256 + s * 32 + quad * 8);

  f32x4 acc[2][4];
#pragma unroll
  for (int i = 0; i < 2; ++i)
#pragma unroll
    for (int j = 0; j < 4; ++j) acc[i][j] = (f32x4){0.f, 0.f, 0.f, 0.f};
#pragma unroll
  for (int s = 0; s < 8; ++s)
#pragma unroll
    for (int j = 0; j < 4; ++j) {
      half8 wb = *(const half8*)(ws16 + (kbase + j) * 256 + s * 32 + quad * 8);  // W_h
#pragma unroll
      for (int i = 0; i < 2; ++i)
        acc[i][j] = __builtin_amdgcn_mfma_f32_16x16x32_f16(ha[i][s], wb, acc[i][j], 0, 0, 0);
    }

  f32x4 bv = *(const f32x4*)(b1 + kbase);
#pragma unroll
  for (int i = 0; i < 2; ++i)
#pragma unroll
    for (int ii = 0; ii < 4; ++ii) {
      f32x4 o = {acc[i][0][ii] + bv[0], acc[i][1][ii] + bv[1],
                 acc[i][2][ii] + bv[2], acc[i][3][ii] + bv[3]};
      *(f32x4*)&th[(row0 + i * 16 + quad * 4 + ii) * 256 + kbase] = o;
    }
}

// ---------------- K2: main. Block = 128 q x 64 k (kt) x 12 c ------------------------
// 4 waves split q (wave w: rows w*32..+31). Lane (quad,r): k = kt*64 + 4r + j.
// LDS: whuL + wuL = exactly 64 KB (both weight slices, XOR-swizzled).
// c-loop: B'[k,h] = h[c,h]*whu + wu built in-register (pk_fma); A = raw u frags.
// acc zero-init (AGPR-class, epilogue-only read). No atomics: plain b128 stores
// into per-kt private `part` region; k_final reduces over kt.
__global__ void __launch_bounds__(256, 2) k_main(
    const float* __restrict__ up, const _Float16* __restrict__ ws16,
    const _Float16* __restrict__ h16, const float* __restrict__ th,
    const float* __restrict__ w2, float* __restrict__ part) {
  __shared__ __align__(16) _Float16 whuL[64 * 256];   // 32 KB
  __shared__ __align__(16) _Float16 wuL[64 * 256];    // 32 KB

  const int tid = threadIdx.x;
  int t = blockIdx.x;                  // 1536 = (b*96 + cc*3 + qt) + 384*kt  (kt SLOW)
  const int kt = t / 384;
  int rest = t % 384;
  const int b = rest / 96;
  rest %= 96;
  const int cc = rest / 3;
  const int qt = rest % 3;
  const int q0 = qt * 128;
  const int c0 = cc * 12;

  const int w = tid >> 6, l = tid & 63, quad = l >> 4, r = l & 15;
  const int kbase = kt * 64 + r * 4;   // lane's 4 k = kbase + j

  const _Float16* Wu = ws16 + 65536;
  const _Float16* Whu = ws16 + 131072;

  // ---- stage both weight k-slices -> LDS, swizzle: slot = (h>>3) ^ ((krel>>2)&7) ----
#pragma unroll
  for (int it = 0; it < 8; ++it) {
    int chunk = tid + it * 256;        // 2048 chunks of 8 halfs per array
    int krel = chunk >> 5;
    int slot = chunk & 31;
    int hsrc = (slot ^ ((krel >> 2) & 7)) * 8;
    *(half8*)&whuL[krel * 256 + slot * 8] =
        *(const half8*)(Whu + (kt * 64 + krel) * 256 + hsrc);
    *(half8*)&wuL[krel * 256 + slot * 8] =
        *(const half8*)(Wu + (kt * 64 + krel) * 256 + hsrc);
  }

  // ---- resident u frags: q = q0 + w*32 + i*16 + r ----
  half8 ufr[2][8];
#pragma unroll
  for (int i = 0; i < 2; ++i) {
    const float* urow = up + (b * 384 + q0 + w * 32 + i * 16 + r) * 256 + quad * 8;
#pragma unroll
    for (int s = 0; s < 8; ++s) ufr[i][s] = cvt8(urow + s * 32);
  }

  __syncthreads();   // LDS ready — the only barrier

  f32x4 w2v = *(const f32x4*)(w2 + kbase);
  const int rs = r & 7;                          // reader-side slot swizzle
  const _Float16* hrow0 = h16 + (b * 384 + c0) * 256 + quad * 8;
  const float* throw0 = th + (b * 384 + c0) * 256 + kbase;
  float* pk = part + kt * 589824 + (b * 384 + c0) * 384 + q0 + w * 32 + quad * 4;

  for (int cp = 0; cp < 6; ++cp) {
    // th' for the two c-rows (held across the s-loop; epilogue-only use)
    f32x4 thv0 = *(const f32x4*)(throw0 + (2 * cp) * 256);
    f32x4 thv1 = *(const f32x4*)(throw0 + (2 * cp + 1) * 256);

    f32x4 acc[2][2][4];
#pragma unroll
    for (int c2 = 0; c2 < 2; ++c2)
#pragma unroll
      for (int i = 0; i < 2; ++i)
#pragma unroll
        for (int j = 0; j < 4; ++j) acc[c2][i][j] = (f32x4){0.f, 0.f, 0.f, 0.f};

#pragma unroll
    for (int s = 0; s < 8; ++s) {
      half8 hc0 = *(const half8*)(hrow0 + (2 * cp) * 256 + s * 32);     // L2, bcast/quad
      half8 hc1 = *(const half8*)(hrow0 + (2 * cp + 1) * 256 + s * 32);
      int slot = (s * 4 + quad) ^ rs;
#pragma unroll
      for (int j = 0; j < 4; ++j) {
        int krel = r * 4 + j;
        half8 wf = *(const half8*)&whuL[krel * 256 + slot * 8];
        half8 uf = *(const half8*)&wuL[krel * 256 + slot * 8];
        half8 bp0 = wf * hc0 + uf;     // v_pk_fma_f16 x4
        half8 bp1 = wf * hc1 + uf;
#pragma unroll
        for (int i = 0; i < 2; ++i) {
          acc[0][i][j] = __builtin_amdgcn_mfma_f32_16x16x32_f16(ufr[i][s], bp0, acc[0][i][j], 0, 0, 0);
          acc[1][i][j] = __builtin_amdgcn_mfma_f32_16x16x32_f16(ufr[i][s], bp1, acc[1][i][j], 0, 0, 0);
        }
      }
    }

    // epilogue: pre1 = acc + th'; layer-2 k-partial; b128 store to private region
#pragma unroll
    for (int c2 = 0; c2 < 2; ++c2) {
      f32x4 thv = c2 ? thv1 : thv0;
#pragma unroll
      for (int i = 0; i < 2; ++i) {
        f32x4 res;
#pragma unroll
        for (int ii = 0; ii < 4; ++ii) {
          float p = 0.f;
#pragma unroll
          for (int j = 0; j < 4; ++j) {
            float base = acc[c2][i][j][ii] + thv[j];
            float tt = fmaf(0.495f, fabsf(base), 0.505f * base);   // leaky algebra
            p = fmaf(w2v[j], tt, p);
          }
          res[ii] = row16_sum(p);
        }
        if (r == 0)
          *(f32x4*)(pk + (2 * cp + c2) * 384 + i * 16) = res;
      }
    }
  }
}

// ---------------- K3: out = leaky(sum_kt part + b2) ---------------------------------
__global__ void k_final(const float* __restrict__ part, const float* __restrict__ b2,
                        float* __restrict__ out) {
  int i = blockIdx.x * 256 + threadIdx.x;        // 589824 exact
  float v = part[i] + part[i + 589824] + part[i + 2 * 589824] + part[i + 3 * 589824];
  out[i] = leaky(v + b2[0]);
}

extern "C" void kernel_launch(void* const* d_in, const int* in_sizes, int n_in,
                              void* d_out, int out_size, void* d_ws, size_t ws_size,
                              hipStream_t stream) {
  const float* hp = (const float*)d_in[0];   // (4,384,256)
  const float* up = (const float*)d_in[1];   // (4,384,256)
  const float* w1 = (const float*)d_in[2];   // (256,768) — axis-0 is k
  const float* b1 = (const float*)d_in[3];   // (256,)
  const float* w2 = (const float*)d_in[4];   // (1,256)
  const float* b2 = (const float*)d_in[5];   // (1,)
  float* out = (float*)d_out;                // (4,384,384)

  _Float16* ws16 = (_Float16*)d_ws;                       // weights fp16
  _Float16* h16 = (_Float16*)((char*)d_ws + 393216);      // h fp16 (1536,256)
  float* th = (float*)((char*)d_ws + 1179648);            // th' (1536,256)
  float* part = (float*)((char*)d_ws + 2752512);          // 4 x (4*384*384)

  k_convert<<<1152, 256, 0, stream>>>(w1, hp, (unsigned int*)d_ws);
  k_pre<<<48, 256, 0, stream>>>(ws16, h16, b1, th);
  k_main<<<1536, 256, 0, stream>>>(up, ws16, h16, th, w2, part);
  k_final<<<2304, 256, 0, stream>>>(part, b2, out);
}